// Round 1
// baseline (804.629 us; speedup 1.0000x reference)
//
#include <hip/hip_runtime.h>
#include <math.h>

#define BB 2048   // batch
#define TT 128    // time steps
#define DD 512    // feature dim
#define NTASK (BB * TT)

// ---------------------------------------------------------------------------
// Kernel A: gi[g][t][b] = sum_d x[b,t,d] * w_ih[g,d]
// One wave (64 lanes) per (b,t) task; each lane covers 8 consecutive d's.
// w_ih slices live in registers (amortized over ~32 tasks per wave).
// Output planes laid out [gate][t*B + b] so kernel B reads coalesced.
// ---------------------------------------------------------------------------
__global__ __launch_bounds__(256) void gi_kernel(const float* __restrict__ x,
                                                 const float* __restrict__ w_ih,
                                                 float* __restrict__ gr,
                                                 float* __restrict__ gz,
                                                 float* __restrict__ gn) {
    const int lane   = threadIdx.x & 63;
    const int wave   = blockIdx.x * (blockDim.x >> 6) + (threadIdx.x >> 6);
    const int nwaves = (gridDim.x * blockDim.x) >> 6;

    const int doff = lane * 8;
    const float4 wr0 = *(const float4*)(w_ih + 0 * DD + doff);
    const float4 wr1 = *(const float4*)(w_ih + 0 * DD + doff + 4);
    const float4 wz0 = *(const float4*)(w_ih + 1 * DD + doff);
    const float4 wz1 = *(const float4*)(w_ih + 1 * DD + doff + 4);
    const float4 wn0 = *(const float4*)(w_ih + 2 * DD + doff);
    const float4 wn1 = *(const float4*)(w_ih + 2 * DD + doff + 4);

    for (int task = wave; task < NTASK; task += nwaves) {
        const float* xp = x + (size_t)task * DD + doff;
        const float4 x0 = *(const float4*)(xp);
        const float4 x1 = *(const float4*)(xp + 4);

        float sr = x0.x * wr0.x + x0.y * wr0.y + x0.z * wr0.z + x0.w * wr0.w +
                   x1.x * wr1.x + x1.y * wr1.y + x1.z * wr1.z + x1.w * wr1.w;
        float sz = x0.x * wz0.x + x0.y * wz0.y + x0.z * wz0.z + x0.w * wz0.w +
                   x1.x * wz1.x + x1.y * wz1.y + x1.z * wz1.z + x1.w * wz1.w;
        float sn = x0.x * wn0.x + x0.y * wn0.y + x0.z * wn0.z + x0.w * wn0.w +
                   x1.x * wn1.x + x1.y * wn1.y + x1.z * wn1.z + x1.w * wn1.w;

        #pragma unroll
        for (int off = 32; off > 0; off >>= 1) {
            sr += __shfl_xor(sr, off);
            sz += __shfl_xor(sz, off);
            sn += __shfl_xor(sn, off);
        }

        if (lane == 0) {
            const int b = task >> 7;     // task = b*TT + t
            const int t = task & (TT - 1);
            gr[t * BB + b] = sr;
            gz[t * BB + b] = sz;
            gn[t * BB + b] = sn;
        }
    }
}

// ---------------------------------------------------------------------------
// Kernel B: per-batch scalar GRU recurrence + running batch-mean per t.
// Thread = batch element. Wave-level shuffle reduce, 1 atomicAdd/wave/t.
// ---------------------------------------------------------------------------
__global__ __launch_bounds__(64) void gru_kernel(const float* __restrict__ gr,
                                                 const float* __restrict__ gz,
                                                 const float* __restrict__ gn,
                                                 const float* __restrict__ h0,
                                                 const float* __restrict__ w_hh,
                                                 const float* __restrict__ b_ih,
                                                 const float* __restrict__ b_hh,
                                                 float* __restrict__ out) {
    const int b = blockIdx.x * 64 + threadIdx.x;

    const float whr = w_hh[0], whz = w_hh[1], whn = w_hh[2];
    const float br  = b_ih[0] + b_hh[0];          // gi bias + gh bias fold for r,z
    const float bz  = b_ih[1] + b_hh[1];
    const float bin_= b_ih[2];
    const float bhn = b_hh[2];

    float h = h0[b];

    for (int t = 0; t < TT; ++t) {
        const float ir  = gr[t * BB + b] + br  + h * whr;
        const float iz  = gz[t * BB + b] + bz  + h * whz;
        const float ghn = h * whn + bhn;          // gh_n kept separate: n = tanh(gi_n + r*gh_n)

        const float r = 1.0f / (1.0f + expf(-ir));
        const float z = 1.0f / (1.0f + expf(-iz));
        const float n = tanhf(gn[t * BB + b] + b_ih[2] - bin_ + bin_ + r * ghn);

        h = (1.0f - z) * n + z * h;

        float s = h;
        #pragma unroll
        for (int off = 32; off > 0; off >>= 1) s += __shfl_xor(s, off);
        if (threadIdx.x == 0) atomicAdd(out + t, s * (1.0f / (float)BB));
    }
}

extern "C" void kernel_launch(void* const* d_in, const int* in_sizes, int n_in,
                              void* d_out, int out_size, void* d_ws, size_t ws_size,
                              hipStream_t stream) {
    const float* x    = (const float*)d_in[0];
    const float* h0   = (const float*)d_in[1];
    const float* w_ih = (const float*)d_in[2];
    const float* w_hh = (const float*)d_in[3];
    const float* b_ih = (const float*)d_in[4];
    const float* b_hh = (const float*)d_in[5];
    float* out = (float*)d_out;

    float* gr = (float*)d_ws;        // [TT][BB]
    float* gz = gr + NTASK;
    float* gn = gz + NTASK;

    // d_out is re-poisoned to 0xAA before every timed call; zero it for atomics.
    hipMemsetAsync(d_out, 0, (size_t)out_size * sizeof(float), stream);

    // 2048 blocks x 4 waves = 8192 waves; 32 (b,t) tasks per wave.
    gi_kernel<<<2048, 256, 0, stream>>>(x, w_ih, gr, gz, gn);
    gru_kernel<<<BB / 64, 64, 0, stream>>>(gr, gz, gn, h0, w_hh, b_ih, b_hh, out);
}